// Round 1
// 211.039 us; speedup vs baseline: 1.0301x; 1.0301x over previous
//
#include <hip/hip_runtime.h>
#include <math.h>

#define NQ    6
#define QDIM  64
#define BB    128
#define CC    64
#define TT    2048
#define DD    256
#define NCH   128
#define CHLEN 16
#define HH    128
#define NCP   60

typedef __bf16 bf16x8 __attribute__((ext_vector_type(8)));
typedef float  f32x4  __attribute__((ext_vector_type(4)));

__device__ __forceinline__ float fast_tanh(float x) {
  float e = __expf(2.f * x);
  return 1.f - 2.f / (e + 1.f);
}

__device__ __forceinline__ float wave_sum(float v) {
#pragma unroll
  for (int off = 32; off >= 1; off >>= 1) v += __shfl_xor(v, off, 64);
  return v;
}

// ---- quantum gates (k3 path keeps the trig-per-gate form; k1 uses fused) ----
__device__ __forceinline__ void g_rx(float& re, float& im, int lane, int m, float half) {
  float c = __cosf(half), s = __sinf(half);
  float pre = __shfl_xor(re, m, 64);
  float pim = __shfl_xor(im, m, 64);
  float nre = c * re + s * pim;
  float nim = c * im - s * pre;
  re = nre; im = nim;
}
__device__ __forceinline__ void g_ry(float& re, float& im, int lane, int m, float half) {
  float c = __cosf(half), s = __sinf(half);
  float pre = __shfl_xor(re, m, 64);
  float pim = __shfl_xor(im, m, 64);
  float sg = (lane & m) ? s : -s;
  re = c * re + sg * pre;
  im = c * im + sg * pim;
}
__device__ __forceinline__ void g_rz(float& re, float& im, int lane, int m, float half) {
  float c = __cosf(half), s = __sinf(half);
  float sg = (lane & m) ? s : -s;
  float nre = c * re - sg * im;
  float nim = c * im + sg * re;
  re = nre; im = nim;
}
__device__ __forceinline__ void g_crx(float& re, float& im, int lane, int mc, int mt, float half) {
  float c = __cosf(half), s = __sinf(half);
  float pre = __shfl_xor(re, mt, 64);
  float pim = __shfl_xor(im, mt, 64);
  if (lane & mc) {
    float nre = c * re + s * pim;
    float nim = c * im - s * pre;
    re = nre; im = nim;
  }
}
__device__ __forceinline__ void ansatz_layer(float& re, float& im, int lane,
                                             const float* p) {
#pragma unroll
  for (int q = 0; q < 6; ++q) {
    int m = 1 << (5 - q);
    g_rx(re, im, lane, m, 0.5f * p[3 * q + 0]);
    g_ry(re, im, lane, m, 0.5f * p[3 * q + 1]);
    g_rz(re, im, lane, m, 0.5f * p[3 * q + 2]);
  }
#pragma unroll
  for (int q = 0; q < 6; ++q)
    g_crx(re, im, lane, 1 << (5 - q), 1 << (5 - ((q + 1) % 6)), 0.5f * p[18 + q]);
#pragma unroll
  for (int q = 5; q >= 0; --q)
    g_crx(re, im, lane, 1 << (5 - q), 1 << (5 - ((q + 5) % 6)), 0.5f * p[24 + (5 - q)]);
}

// ============ K0: fused-weight prep (fp32 contractions, then split-bf16) ====
__global__ __launch_bounds__(256) void k0_prep(
    const float* __restrict__ emb_w, const float* __restrict__ emb_b,
    const float* __restrict__ att_w1, const float* __restrict__ att_b1,
    const float* __restrict__ proj_w, const float* __restrict__ proj_b,
    __bf16* __restrict__ WfH, __bf16* __restrict__ WfL,
    __bf16* __restrict__ PfH, __bf16* __restrict__ PfL,
    float* __restrict__ b_fused, float* __restrict__ pb_fused) {
  int idx = blockIdx.x * 256 + threadIdx.x;
  if (idx < 8192) {                         // W_fusedT
    int j = idx & 127, k = idx >> 7;
    float a = 0.f;
    for (int d = 0; d < 256; ++d)
      a = fmaf(emb_w[k * 256 + d], att_w1[d * 128 + j], a);
    __bf16 h = (__bf16)a;
    WfH[j * 64 + k] = h; WfL[j * 64 + k] = (__bf16)(a - (float)h);
  } else if (idx < 12288) {                 // P_fusedT
    int i = idx - 8192;
    int n = i & 63, k = i >> 6;
    float a = 0.f;
    if (n < 60)
      for (int d = 0; d < 256; ++d)
        a = fmaf(emb_w[k * 256 + d], proj_w[d * 60 + n], a);
    __bf16 h = (__bf16)a;
    PfH[n * 64 + k] = h; PfL[n * 64 + k] = (__bf16)(a - (float)h);
  } else if (idx < 12416) {                 // b_fused
    int j = idx - 12288;
    float a = att_b1[j];
    for (int d = 0; d < 256; ++d) a = fmaf(emb_b[d], att_w1[d * 128 + j], a);
    b_fused[j] = a;
  } else if (idx < 12480) {                 // pb_fused
    int n = idx - 12416;
    float a = 0.f;
    if (n < 60) {
      a = proj_b[n];
      for (int d = 0; d < 256; ++d) a = fmaf(emb_b[d], proj_w[d * 60 + n], a);
    }
    pb_fused[n] = a;
  }
}

// ============ K1: fused h-GEMM + softmax + xagg + params + ansatz ============
// Phases (each barrier-separated):
//  A stage x->xtile | B split xtile->afH/afL once (dedup of 4x/wave cvt)
//  C MFMA GEMM_h + tanh/score epilogue | D 32-thread parallel softmax
//  E xagg (fp32 exact) + write bf16-split of xagg once
//  F params GEMM + sigmoid + CRX (cos,sin) precompute (per-param lane)
//  G fused 1q matrices U = Rz*Ry*Rx per (chunk,layer,qubit) -- 24 threads
//  H ansatz: 12 fused 1q + 24 CRX per wave, zero transcendentals in loop
// LDS: xtile(8704) + scoreS(512) + 8KB union(afH/afL <-> post-GEMM smalls)
__global__ __launch_bounds__(256) void k1_fused(
    const float* __restrict__ x, const float* __restrict__ att_w2,
    const __bf16* __restrict__ WfH, const __bf16* __restrict__ WfL,
    const __bf16* __restrict__ PfH, const __bf16* __restrict__ PfL,
    const float* __restrict__ b_fused, const float* __restrict__ pb_fused,
    float2* __restrict__ evolved) {
  const int blk = blockIdx.x;            // 8192 = 128 b x 64 chunk-pairs
  const int b = blk >> 6, cp = blk & 63;
  const int tid = threadIdx.x, wv = tid >> 6, lane = tid & 63;
  const int l15 = lane & 15, quad = lane >> 4;

  __shared__ float xtile[32][68];        // x^T [t][k] fp32 (word-stride 68)
  __shared__ float scoreS[4][32];
  __shared__ float4 uniF4[512];          // 8 KB phase-aliased region
  char* uni = (char*)uniF4;
  // phase B-C view:
  bf16x8* afH = (bf16x8*)uni;                  // [mt][ks][64]  (4 KB)
  bf16x8* afL = (bf16x8*)(uni + 4096);         // (4 KB)
  // phase D-H view (dead vs afH/afL by barriers):
  float*  wSm     = (float*)uni;               // [2][16]   @0    (128)
  __bf16* axH     = (__bf16*)(uni + 128);      // [2][64]   @128  (256)
  __bf16* axL     = (__bf16*)(uni + 384);      // [2][64]   @384  (256)
  float*  paramsS = (float*)(uni + 640);       // [2][60]   @640  (480)
  float4* matS    = (float4*)(uni + 1120);     // [2][12][2]@1120 (768)
  float2* crxS    = (float2*)(uni + 1888);     // [2][24]   @1888 (384)

  {  // A: stage x[b, k, cp*32+t] -> xtile[t][k]; 2 passes, coalesced 16B loads
#pragma unroll
    for (int pass = 0; pass < 2; ++pass) {
      int k = pass * 32 + (tid >> 3), t4 = tid & 7;
      float4 v = *(const float4*)(x + ((size_t)(b * 64 + k)) * 2048 + cp * 32 + t4 * 4);
      xtile[t4 * 4 + 0][k] = v.x; xtile[t4 * 4 + 1][k] = v.y;
      xtile[t4 * 4 + 2][k] = v.z; xtile[t4 * 4 + 3][k] = v.w;
    }
  }
  __syncthreads();

  {  // B: one thread per (mt,ks,lane) fragment: split-bf16 convert ONCE
    const int mt = tid >> 7, ks = (tid >> 6) & 1, ln = tid & 63;
    const float* src = &xtile[mt * 16 + (ln & 15)][ks * 32 + (ln >> 4) * 8];
    float4 u0 = *(const float4*)src, u1 = *(const float4*)(src + 4);
    float vals[8] = {u0.x, u0.y, u0.z, u0.w, u1.x, u1.y, u1.z, u1.w};
    bf16x8 h, l;
#pragma unroll
    for (int j = 0; j < 8; ++j) {
      __bf16 hh = (__bf16)vals[j];
      h[j] = hh;
      l[j] = (__bf16)(vals[j] - (float)hh);
    }
    afH[(mt * 2 + ks) * 64 + ln] = h;
    afL[(mt * 2 + ks) * 64 + ln] = l;
  }
  __syncthreads();

  // ---- C: GEMM_h: h_pre[32][128] = x^T @ W_fused; wave owns j = wv*32..+31 --
  f32x4 acc[2][2];                       // [mt][jt]
#pragma unroll
  for (int mt = 0; mt < 2; ++mt)
#pragma unroll
    for (int jt = 0; jt < 2; ++jt) acc[mt][jt] = (f32x4){0.f, 0.f, 0.f, 0.f};
#pragma unroll
  for (int mt = 0; mt < 2; ++mt) {
    bf16x8 ah[2], al[2];
#pragma unroll
    for (int ks = 0; ks < 2; ++ks) {     // linear, conflict-free b128 reads
      ah[ks] = afH[(mt * 2 + ks) * 64 + lane];
      al[ks] = afL[(mt * 2 + ks) * 64 + lane];
    }
#pragma unroll
    for (int jt = 0; jt < 2; ++jt)
#pragma unroll
      for (int ks = 0; ks < 2; ++ks) {
        const size_t row = (size_t)(wv * 32 + jt * 16 + l15) * 64 + ks * 32 + 8 * quad;
        bf16x8 bh = *(const bf16x8*)(WfH + row);
        bf16x8 bl = *(const bf16x8*)(WfL + row);
        acc[mt][jt] = __builtin_amdgcn_mfma_f32_16x16x32_bf16(ah[ks], bh, acc[mt][jt], 0, 0, 0);
        acc[mt][jt] = __builtin_amdgcn_mfma_f32_16x16x32_bf16(al[ks], bh, acc[mt][jt], 0, 0, 0);
        acc[mt][jt] = __builtin_amdgcn_mfma_f32_16x16x32_bf16(ah[ks], bl, acc[mt][jt], 0, 0, 0);
      }
  }
  {  // scores epilogue: tanh, * w2, reduce over the 16 j's in l15
    float w2v[2], b1v[2];
#pragma unroll
    for (int jt = 0; jt < 2; ++jt) {
      int j = wv * 32 + jt * 16 + l15;
      w2v[jt] = att_w2[j];
      b1v[jt] = b_fused[j];
    }
#pragma unroll
    for (int mt = 0; mt < 2; ++mt)
#pragma unroll
      for (int r = 0; r < 4; ++r) {
        float sc = fast_tanh(acc[mt][0][r] + b1v[0]) * w2v[0] +
                   fast_tanh(acc[mt][1][r] + b1v[1]) * w2v[1];
        sc += __shfl_xor(sc, 1, 64);
        sc += __shfl_xor(sc, 2, 64);
        sc += __shfl_xor(sc, 4, 64);
        sc += __shfl_xor(sc, 8, 64);
        if (l15 == 0) scoreS[wv][mt * 16 + quad * 4 + r] = sc;
      }
  }
  __syncthreads();

  if (tid < 32) {  // D: parallel softmax, 16 lanes per chunk (att_b2 dropped)
    const int c = tid >> 4, t = tid & 15, ct = c * 16 + t;
    float s = (scoreS[0][ct] + scoreS[1][ct]) + (scoreS[2][ct] + scoreS[3][ct]);
    float mx = s;
    mx = fmaxf(mx, __shfl_xor(mx, 1, 64));
    mx = fmaxf(mx, __shfl_xor(mx, 2, 64));
    mx = fmaxf(mx, __shfl_xor(mx, 4, 64));
    mx = fmaxf(mx, __shfl_xor(mx, 8, 64));
    float e = __expf(s - mx);
    float sum = e;
    sum += __shfl_xor(sum, 1, 64);
    sum += __shfl_xor(sum, 2, 64);
    sum += __shfl_xor(sum, 4, 64);
    sum += __shfl_xor(sum, 8, 64);
    wSm[ct] = e / sum;
  }
  __syncthreads();

  if (tid < 128) {  // E: xagg[c][k] exact fp32, then bf16-split ONCE
    const int c = tid >> 6, k = tid & 63;
    float a = 0.f;
#pragma unroll
    for (int t = 0; t < 16; ++t) a = fmaf(wSm[c * 16 + t], xtile[c * 16 + t][k], a);
    __bf16 h = (__bf16)a;
    axH[c * 64 + k] = h;
    axL[c * 64 + k] = (__bf16)(a - (float)h);
  }
  __syncthreads();

  {  // F: params[2][60] = sigmoid(xagg @ P_fused + pb); + CRX trig precompute
    const int jout = wv * 16 + l15;
    f32x4 acc3 = (f32x4){0.f, 0.f, 0.f, 0.f};
#pragma unroll
    for (int ks = 0; ks < 2; ++ks) {
      const size_t row = (size_t)jout * 64 + ks * 32 + 8 * quad;
      bf16x8 bh = *(const bf16x8*)(PfH + row);
      bf16x8 bl = *(const bf16x8*)(PfL + row);
      bf16x8 ax = (bf16x8)(__bf16)0.f, alx = (bf16x8)(__bf16)0.f;
      if (l15 < 2) {
        ax  = *(const bf16x8*)(axH + l15 * 64 + ks * 32 + 8 * quad);
        alx = *(const bf16x8*)(axL + l15 * 64 + ks * 32 + 8 * quad);
      }
      acc3 = __builtin_amdgcn_mfma_f32_16x16x32_bf16(ax, bh, acc3, 0, 0, 0);
      acc3 = __builtin_amdgcn_mfma_f32_16x16x32_bf16(alx, bh, acc3, 0, 0, 0);
      acc3 = __builtin_amdgcn_mfma_f32_16x16x32_bf16(ax, bl, acc3, 0, 0, 0);
    }
    if (jout < 60 && quad == 0) {
      float pbias = pb_fused[jout];
      const int layer = (jout >= 30) ? 1 : 0;
      const int pm = jout - layer * 30;
#pragma unroll
      for (int r = 0; r < 2; ++r) {
        float a = acc3[r] + pbias;
        float p = 1.f / (1.f + __expf(-a));
        paramsS[r * 60 + jout] = p;
        if (pm >= 18) {                 // CRX param: stash (cos,sin) of half
          float sn, cs;
          __sincosf(0.5f * p, &sn, &cs);
          crxS[r * 24 + layer * 12 + (pm - 18)] = make_float2(cs, sn);
        }
      }
    }
  }
  __syncthreads();

  if (tid < 24) {  // G: fused 1q unitary U = Rz*Ry*Rx per (chunk,layer,qubit)
    const int r = tid / 12, g = tid % 12;      // g = layer*6 + q
    const float* pp = paramsS + r * 60 + (g / 6) * 30 + (g % 6) * 3;
    float sa, ca, sb, cb, sg, cg;
    __sincosf(0.5f * pp[0], &sa, &ca);
    __sincosf(0.5f * pp[1], &sb, &cb);
    __sincosf(0.5f * pp[2], &sg, &cg);
    // M = Ry*Rx
    float m00r = cb * ca, m00i = sb * sa;
    float m01r = -sb * ca, m01i = -cb * sa;
    float m10r = sb * ca, m10i = -cb * sa;
    float m11r = cb * ca, m11i = -sb * sa;
    // row0 *= e^{-i g}; row1 *= e^{+i g}; store per-bit {diag, offdiag}
    float4 b0, b1;
    b0.x = cg * m00r + sg * m00i;  b0.y = cg * m00i - sg * m00r;   // U00
    b0.z = cg * m01r + sg * m01i;  b0.w = cg * m01i - sg * m01r;   // U01
    b1.x = cg * m11r - sg * m11i;  b1.y = cg * m11i + sg * m11r;   // U11
    b1.z = cg * m10r - sg * m10i;  b1.w = cg * m10i + sg * m10r;   // U10
    matS[(r * 12 + g) * 2 + 0] = b0;
    matS[(r * 12 + g) * 2 + 1] = b1;
  }
  __syncthreads();

  // ---- H: waves 0,1 evolve their chunk's statevector (trig-free loop) ----
  if (wv < 2) {
    float re = (lane == 0) ? 1.f : 0.f, im = 0.f;
    const float4* mats = matS + wv * 24;   // [12][2]
    const float2* crxs = crxS + wv * 24;   // [2][12]
#pragma unroll
    for (int l = 0; l < 2; ++l) {
#pragma unroll
      for (int q = 0; q < 6; ++q) {        // fused RX*RY*RZ
        const int m = 1 << (5 - q);
        float4 M = mats[(l * 6 + q) * 2 + ((lane & m) ? 1 : 0)];
        float pre = __shfl_xor(re, m, 64);
        float pim = __shfl_xor(im, m, 64);
        float nre = M.x * re - M.y * im + M.z * pre - M.w * pim;
        float nim = M.x * im + M.y * re + M.z * pim + M.w * pre;
        re = nre; im = nim;
      }
#pragma unroll
      for (int e = 0; e < 12; ++e) {       // ring CRX fwd then bwd
        const int q = (e < 6) ? e : (11 - e);
        const int mc = 1 << (5 - q);
        const int mt = (e < 6) ? (1 << (5 - ((q + 1) % 6)))
                               : (1 << (5 - ((q + 5) % 6)));
        float2 cs = crxs[l * 12 + e];
        float pre = __shfl_xor(re, mt, 64);
        float pim = __shfl_xor(im, mt, 64);
        float nre = fmaf(cs.y, pim, cs.x * re);
        float nim = fmaf(-cs.y, pre, cs.x * im);
        bool act = (lane & mc) != 0;
        re = act ? nre : re;
        im = act ? nim : im;
      }
    }
    evolved[((size_t)b * NCH + cp * 2 + wv) * QDIM + lane] = make_float2(re, im);
  }
}

// ============ K3: LCU mix + qff ansatz + expvals + head (512 thr) ============
__global__ __launch_bounds__(512) void k3_head(
    const float2* __restrict__ evolved, const float* __restrict__ mix_re,
    const float* __restrict__ mix_im, const float* __restrict__ qff,
    const float* __restrict__ out_w, const float* __restrict__ out_b,
    const float* __restrict__ ln_g, const float* __restrict__ ln_b,
    const float* __restrict__ cls_w1, const float* __restrict__ cls_b1,
    const float* __restrict__ cls_w2, const float* __restrict__ cls_b2,
    float* __restrict__ outp) {
  const int b = blockIdx.x, tid = threadIdx.x, wv = tid >> 6, lane = tid & 63;
  __shared__ float mreS[8][64], mimS[8][64];
  __shared__ float qfeatS[18];
  __shared__ float outS[DD];
  __shared__ float redS[8];
  __shared__ float clsR[2][DD];

  float are = 0.f, aim = 0.f;
#pragma unroll 4
  for (int t = wv * 16; t < wv * 16 + 16; ++t) {
    float2 e = evolved[((size_t)b * NCH + t) * QDIM + lane];
    float cr = mix_re[t], ci = mix_im[t];
    are = fmaf(cr, e.x, are); are = fmaf(-ci, e.y, are);
    aim = fmaf(cr, e.y, aim); aim = fmaf(ci, e.x, aim);
  }
  mreS[wv][lane] = are; mimS[wv][lane] = aim;
  __syncthreads();

  if (wv == 0) {
    float r0 = mix_re[lane], i0 = mix_im[lane];
    float r1 = mix_re[lane + 64], i1 = mix_im[lane + 64];
    float sp = sqrtf(r0 * r0 + i0 * i0) + sqrtf(r1 * r1 + i1 * i1);
    float S = wave_sum(sp) + 1e-8f;
    float re = 0.f, im = 0.f;
#pragma unroll
    for (int w = 0; w < 8; ++w) { re += mreS[w][lane]; im += mimS[w][lane]; }
    float invS = 1.f / S;
    re *= invS; im *= invS;
    float n2 = wave_sum(re * re + im * im);
    float scl = 1.f / (sqrtf(n2) + 1e-9f);
    re *= scl; im *= scl;
    float qp[30];
#pragma unroll
    for (int i = 0; i < 30; ++i) qp[i] = qff[i];
    ansatz_layer(re, im, lane, qp);
#pragma unroll
    for (int q = 0; q < 6; ++q) {
      int m = 1 << (5 - q);
      float pre = __shfl_xor(re, m, 64), pim = __shfl_xor(im, m, 64);
      float vx = re * pre + im * pim;
      float vy = (lane & m) ? (im * pre - re * pim) : (re * pim - im * pre);
      float vz = (lane & m) ? -(re * re + im * im) : (re * re + im * im);
      vx = wave_sum(vx); vy = wave_sum(vy); vz = wave_sum(vz);
      if (lane == 0) { qfeatS[q] = vx; qfeatS[6 + q] = vy; qfeatS[12 + q] = vz; }
    }
  }
  __syncthreads();

  float o = 0.f, dv = 0.f;
  if (tid < 256) {
    o = out_b[tid];
#pragma unroll
    for (int k = 0; k < 18; ++k) o = fmaf(qfeatS[k], out_w[k * DD + tid], o);
    float s1 = wave_sum(o);
    if (lane == 0) redS[wv] = s1;
  }
  __syncthreads();
  float mu = (redS[0] + redS[1] + redS[2] + redS[3]) * (1.f / 256.f);
  if (tid < 256) {
    dv = o - mu;
    float s2 = wave_sum(dv * dv);
    if (lane == 0) redS[wv] = s2;
  }
  __syncthreads();
  float var = (redS[0] + redS[1] + redS[2] + redS[3]) * (1.f / 256.f);
  if (tid < 256) {
    outS[tid] = dv / sqrtf(var + 1e-5f) * ln_g[tid] + ln_b[tid];
  }
  __syncthreads();

  {
    const int dd = tid & 255, hh = tid >> 8;
    float r = (hh == 0) ? cls_b1[dd] : 0.f;
#pragma unroll 8
    for (int d = hh * 128; d < hh * 128 + 128; ++d)
      r = fmaf(outS[d], cls_w1[(size_t)d * DD + dd], r);
    clsR[hh][dd] = r;
  }
  __syncthreads();
  if (tid < 256) {
    float r = fmaxf(clsR[0][tid] + clsR[1][tid], 0.f);
    float p0 = wave_sum(r * cls_w2[tid * 2 + 0]);
    float p1 = wave_sum(r * cls_w2[tid * 2 + 1]);
    if (lane == 0) { mreS[0][wv] = p0; mreS[1][wv] = p1; }
  }
  __syncthreads();
  if (tid == 0) {
    outp[b * 2 + 0] = (mreS[0][0] + mreS[0][1]) + (mreS[0][2] + mreS[0][3]) + cls_b2[0];
    outp[b * 2 + 1] = (mreS[1][0] + mreS[1][1]) + (mreS[1][2] + mreS[1][3]) + cls_b2[1];
  }
}

extern "C" void kernel_launch(void* const* d_in, const int* in_sizes, int n_in,
                              void* d_out, int out_size, void* d_ws, size_t ws_size,
                              hipStream_t stream) {
  const float* x      = (const float*)d_in[0];
  const float* emb_w  = (const float*)d_in[1];
  const float* emb_b  = (const float*)d_in[2];
  const float* att_w1 = (const float*)d_in[3];
  const float* att_b1 = (const float*)d_in[4];
  const float* att_w2 = (const float*)d_in[5];
  // d_in[6] att_b2: unused (softmax shift-invariant)
  const float* proj_w = (const float*)d_in[7];
  const float* proj_b = (const float*)d_in[8];
  const float* mix_re = (const float*)d_in[9];
  const float* mix_im = (const float*)d_in[10];
  const float* qff    = (const float*)d_in[11];
  const float* out_w  = (const float*)d_in[12];
  const float* out_b  = (const float*)d_in[13];
  const float* ln_g   = (const float*)d_in[14];
  const float* ln_b   = (const float*)d_in[15];
  const float* cls_w1 = (const float*)d_in[16];
  const float* cls_b1 = (const float*)d_in[17];
  const float* cls_w2 = (const float*)d_in[18];
  const float* cls_b2 = (const float*)d_in[19];

  char* ws = (char*)d_ws;
  float2* evolved = (float2*)ws;                     // 16384*64*8 = 8,388,608
  size_t off = 8388608;
  __bf16* WfH = (__bf16*)(ws + off); off += 16384;   // 128x64 bf16
  __bf16* WfL = (__bf16*)(ws + off); off += 16384;
  __bf16* PfH = (__bf16*)(ws + off); off += 8192;    // 64x64 bf16
  __bf16* PfL = (__bf16*)(ws + off); off += 8192;
  float* b_fused  = (float*)(ws + off); off += 512;
  float* pb_fused = (float*)(ws + off); off += 256;

  k0_prep<<<49, 256, 0, stream>>>(emb_w, emb_b, att_w1, att_b1, proj_w, proj_b,
                                  WfH, WfL, PfH, PfL, b_fused, pb_fused);
  k1_fused<<<BB * 64, 256, 0, stream>>>(
      x, att_w2, WfH, WfL, PfH, PfL, b_fused, pb_fused, evolved);
  k3_head<<<BB, 512, 0, stream>>>(evolved, mix_re, mix_im, qff, out_w, out_b,
                                  ln_g, ln_b, cls_w1, cls_b1, cls_w2, cls_b2,
                                  (float*)d_out);
}

// Round 2
// 203.918 us; speedup vs baseline: 1.0661x; 1.0349x over previous
//
#include <hip/hip_runtime.h>
#include <math.h>

#define NQ    6
#define QDIM  64
#define BB    128
#define CC    64
#define TT    2048
#define DD    256
#define NCH   128
#define CHLEN 16
#define HH    128
#define NCP   60

typedef __bf16 bf16x8 __attribute__((ext_vector_type(8)));
typedef float  f32x4  __attribute__((ext_vector_type(4)));

__device__ __forceinline__ float fast_tanh(float x) {
  float e = __expf(2.f * x);
  return 1.f - 2.f / (e + 1.f);
}

__device__ __forceinline__ float wave_sum(float v) {
#pragma unroll
  for (int off = 32; off >= 1; off >>= 1) v += __shfl_xor(v, off, 64);
  return v;
}

// ---- quantum gates (k3 path keeps the trig-per-gate form; k1 uses fused) ----
__device__ __forceinline__ void g_rx(float& re, float& im, int lane, int m, float half) {
  float c = __cosf(half), s = __sinf(half);
  float pre = __shfl_xor(re, m, 64);
  float pim = __shfl_xor(im, m, 64);
  float nre = c * re + s * pim;
  float nim = c * im - s * pre;
  re = nre; im = nim;
}
__device__ __forceinline__ void g_ry(float& re, float& im, int lane, int m, float half) {
  float c = __cosf(half), s = __sinf(half);
  float pre = __shfl_xor(re, m, 64);
  float pim = __shfl_xor(im, m, 64);
  float sg = (lane & m) ? s : -s;
  re = c * re + sg * pre;
  im = c * im + sg * pim;
}
__device__ __forceinline__ void g_rz(float& re, float& im, int lane, int m, float half) {
  float c = __cosf(half), s = __sinf(half);
  float sg = (lane & m) ? s : -s;
  float nre = c * re - sg * im;
  float nim = c * im + sg * re;
  re = nre; im = nim;
}
__device__ __forceinline__ void g_crx(float& re, float& im, int lane, int mc, int mt, float half) {
  float c = __cosf(half), s = __sinf(half);
  float pre = __shfl_xor(re, mt, 64);
  float pim = __shfl_xor(im, mt, 64);
  if (lane & mc) {
    float nre = c * re + s * pim;
    float nim = c * im - s * pre;
    re = nre; im = nim;
  }
}
__device__ __forceinline__ void ansatz_layer(float& re, float& im, int lane,
                                             const float* p) {
#pragma unroll
  for (int q = 0; q < 6; ++q) {
    int m = 1 << (5 - q);
    g_rx(re, im, lane, m, 0.5f * p[3 * q + 0]);
    g_ry(re, im, lane, m, 0.5f * p[3 * q + 1]);
    g_rz(re, im, lane, m, 0.5f * p[3 * q + 2]);
  }
#pragma unroll
  for (int q = 0; q < 6; ++q)
    g_crx(re, im, lane, 1 << (5 - q), 1 << (5 - ((q + 1) % 6)), 0.5f * p[18 + q]);
#pragma unroll
  for (int q = 5; q >= 0; --q)
    g_crx(re, im, lane, 1 << (5 - q), 1 << (5 - ((q + 5) % 6)), 0.5f * p[24 + (5 - q)]);
}

// ============ K0: fused-weight prep, 8-way split-K (390 blocks) =============
// Each output computed by 8 consecutive lanes (32 fma each), combined via
// 3 shfl_xor steps in the aligned 8-lane group. All branch-region boundaries
// are multiples of 8 so shuffle groups never straddle regions.
__global__ __launch_bounds__(256) void k0_prep(
    const float* __restrict__ emb_w, const float* __restrict__ emb_b,
    const float* __restrict__ att_w1, const float* __restrict__ att_b1,
    const float* __restrict__ proj_w, const float* __restrict__ proj_b,
    __bf16* __restrict__ WfH, __bf16* __restrict__ WfL,
    __bf16* __restrict__ PfH, __bf16* __restrict__ PfL,
    float* __restrict__ b_fused, float* __restrict__ pb_fused) {
  int idx = blockIdx.x * 256 + threadIdx.x;
  if (idx < 65536) {                        // W_fusedT: 8192 outs x 8 parts
    int out = idx >> 3, part = idx & 7;
    int j = out & 127, k = out >> 7;
    int d0 = part * 32;
    float a = 0.f;
#pragma unroll 8
    for (int d = d0; d < d0 + 32; ++d)
      a = fmaf(emb_w[k * 256 + d], att_w1[d * 128 + j], a);
    a += __shfl_xor(a, 1, 64); a += __shfl_xor(a, 2, 64); a += __shfl_xor(a, 4, 64);
    if (part == 0) {
      __bf16 h = (__bf16)a;
      WfH[j * 64 + k] = h; WfL[j * 64 + k] = (__bf16)(a - (float)h);
    }
  } else if (idx < 98304) {                 // P_fusedT: 4096 outs x 8 parts
    int i2 = idx - 65536;
    int out = i2 >> 3, part = i2 & 7;
    int n = out & 63, k = out >> 6;
    float a = 0.f;
    if (n < 60) {
      int d0 = part * 32;
#pragma unroll 8
      for (int d = d0; d < d0 + 32; ++d)
        a = fmaf(emb_w[k * 256 + d], proj_w[d * 60 + n], a);
    }
    a += __shfl_xor(a, 1, 64); a += __shfl_xor(a, 2, 64); a += __shfl_xor(a, 4, 64);
    if (part == 0) {
      __bf16 h = (__bf16)a;
      PfH[n * 64 + k] = h; PfL[n * 64 + k] = (__bf16)(a - (float)h);
    }
  } else if (idx < 99328) {                 // b_fused: 128 outs x 8
    int i3 = idx - 98304;
    int out = i3 >> 3, part = i3 & 7;
    float a = (part == 0) ? att_b1[out] : 0.f;
    int d0 = part * 32;
#pragma unroll 8
    for (int d = d0; d < d0 + 32; ++d)
      a = fmaf(emb_b[d], att_w1[d * 128 + out], a);
    a += __shfl_xor(a, 1, 64); a += __shfl_xor(a, 2, 64); a += __shfl_xor(a, 4, 64);
    if (part == 0) b_fused[out] = a;
  } else if (idx < 99840) {                 // pb_fused: 64 outs x 8
    int i4 = idx - 99328;
    int out = i4 >> 3, part = i4 & 7;
    float a = 0.f;
    if (out < 60) {
      if (part == 0) a = proj_b[out];
      int d0 = part * 32;
#pragma unroll 8
      for (int d = d0; d < d0 + 32; ++d)
        a = fmaf(emb_b[d], proj_w[d * 60 + out], a);
    }
    a += __shfl_xor(a, 1, 64); a += __shfl_xor(a, 2, 64); a += __shfl_xor(a, 4, 64);
    if (part == 0) pb_fused[out] = a;
  }
}

// ============ K1: fused h-GEMM + softmax + xagg + params + ansatz ============
// 4 chunks per block (64 t-rows), grid 4096. Phases barrier-separated:
//  A stage x->xtile(64x64) | B split->frags once | C GEMM (48 MFMA) + scores
//  D softmax (64 thr) | E xagg + bf16 split (256 thr)
//  F params GEMM (6 MFMA -> 4 chunks) + CRX trig | G fused 1q mats (48 thr)
//  H ansatz: ALL 4 waves, 1 chunk each, trig-free
__global__ __launch_bounds__(256) void k1_fused(
    const float* __restrict__ x, const float* __restrict__ att_w2,
    const __bf16* __restrict__ WfH, const __bf16* __restrict__ WfL,
    const __bf16* __restrict__ PfH, const __bf16* __restrict__ PfL,
    const float* __restrict__ b_fused, const float* __restrict__ pb_fused,
    float2* __restrict__ evolved) {
  const int blk = blockIdx.x;            // 4096 = 128 b x 32 chunk-quads
  const int b = blk >> 5, cq = blk & 31;
  const int tid = threadIdx.x, wv = tid >> 6, lane = tid & 63;
  const int l15 = lane & 15, quad = lane >> 4;

  __shared__ float xtile[64][68];        // x^T [t][k] fp32 (word-stride 68)
  __shared__ float scoreS[4][64];
  __shared__ float4 uniF4[1024];         // 16 KB phase-aliased region
  char* uni = (char*)uniF4;
  // phase B-C view:
  bf16x8* afH = (bf16x8*)uni;                  // [4mt][2ks][64]  (8 KB)
  bf16x8* afL = (bf16x8*)(uni + 8192);         // (8 KB)
  // phase D-H view (dead vs afH/afL by barriers):
  float*  wSm     = (float*)uni;               // [4][16]   @0     (256)
  __bf16* axH     = (__bf16*)(uni + 256);      // [4][64]   @256   (512)
  __bf16* axL     = (__bf16*)(uni + 768);      // [4][64]   @768   (512)
  float*  paramsS = (float*)(uni + 1280);      // [4][60]   @1280  (960)
  float4* matS    = (float4*)(uni + 2240);     // [4][12][2]@2240  (3072)
  float2* crxS    = (float2*)(uni + 5312);     // [4][24]   @5312  (768)

  {  // A: stage x[b, k, cq*64+t] -> xtile[t][k]; 4 passes, coalesced 16B loads
#pragma unroll
    for (int pass = 0; pass < 4; ++pass) {
      int k = pass * 16 + (tid >> 4), t4 = tid & 15;
      float4 v = *(const float4*)(x + ((size_t)(b * 64 + k)) * 2048 + cq * 64 + t4 * 4);
      xtile[t4 * 4 + 0][k] = v.x; xtile[t4 * 4 + 1][k] = v.y;
      xtile[t4 * 4 + 2][k] = v.z; xtile[t4 * 4 + 3][k] = v.w;
    }
  }
  __syncthreads();

  {  // B: 512 frag items, split-bf16 convert ONCE
#pragma unroll
    for (int it = 0; it < 2; ++it) {
      int item = it * 256 + tid;
      int ln = item & 63, ks = (item >> 6) & 1, mt = item >> 7;
      const float* src = &xtile[mt * 16 + (ln & 15)][ks * 32 + (ln >> 4) * 8];
      float4 u0 = *(const float4*)src, u1 = *(const float4*)(src + 4);
      float vals[8] = {u0.x, u0.y, u0.z, u0.w, u1.x, u1.y, u1.z, u1.w};
      bf16x8 h, l;
#pragma unroll
      for (int j = 0; j < 8; ++j) {
        __bf16 hh = (__bf16)vals[j];
        h[j] = hh;
        l[j] = (__bf16)(vals[j] - (float)hh);
      }
      afH[(mt * 2 + ks) * 64 + ln] = h;
      afL[(mt * 2 + ks) * 64 + ln] = l;
    }
  }
  __syncthreads();

  // ---- C: GEMM_h: h_pre[64][128] = x^T @ W_fused; wave owns j = wv*32..+31 --
  f32x4 acc[4][2];                       // [mt][jt]
#pragma unroll
  for (int mt = 0; mt < 4; ++mt)
#pragma unroll
    for (int jt = 0; jt < 2; ++jt) acc[mt][jt] = (f32x4){0.f, 0.f, 0.f, 0.f};
#pragma unroll
  for (int ks = 0; ks < 2; ++ks) {       // A-frags and B-frags each loaded once
    bf16x8 ah[4], al[4];
#pragma unroll
    for (int mt = 0; mt < 4; ++mt) {
      ah[mt] = afH[(mt * 2 + ks) * 64 + lane];
      al[mt] = afL[(mt * 2 + ks) * 64 + lane];
    }
#pragma unroll
    for (int jt = 0; jt < 2; ++jt) {
      const size_t row = (size_t)(wv * 32 + jt * 16 + l15) * 64 + ks * 32 + 8 * quad;
      bf16x8 bh = *(const bf16x8*)(WfH + row);
      bf16x8 bl = *(const bf16x8*)(WfL + row);
#pragma unroll
      for (int mt = 0; mt < 4; ++mt) {
        acc[mt][jt] = __builtin_amdgcn_mfma_f32_16x16x32_bf16(ah[mt], bh, acc[mt][jt], 0, 0, 0);
        acc[mt][jt] = __builtin_amdgcn_mfma_f32_16x16x32_bf16(al[mt], bh, acc[mt][jt], 0, 0, 0);
        acc[mt][jt] = __builtin_amdgcn_mfma_f32_16x16x32_bf16(ah[mt], bl, acc[mt][jt], 0, 0, 0);
      }
    }
  }
  {  // scores epilogue: tanh, * w2, reduce over the 16 j's in l15
    float w2v[2], b1v[2];
#pragma unroll
    for (int jt = 0; jt < 2; ++jt) {
      int j = wv * 32 + jt * 16 + l15;
      w2v[jt] = att_w2[j];
      b1v[jt] = b_fused[j];
    }
#pragma unroll
    for (int mt = 0; mt < 4; ++mt)
#pragma unroll
      for (int r = 0; r < 4; ++r) {
        float sc = fast_tanh(acc[mt][0][r] + b1v[0]) * w2v[0] +
                   fast_tanh(acc[mt][1][r] + b1v[1]) * w2v[1];
        sc += __shfl_xor(sc, 1, 64);
        sc += __shfl_xor(sc, 2, 64);
        sc += __shfl_xor(sc, 4, 64);
        sc += __shfl_xor(sc, 8, 64);
        if (l15 == 0) scoreS[wv][mt * 16 + quad * 4 + r] = sc;
      }
  }
  __syncthreads();

  if (tid < 64) {  // D: parallel softmax, 16 lanes per chunk (att_b2 dropped)
    const int c = tid >> 4, t = tid & 15, ct = c * 16 + t;
    float s = (scoreS[0][ct] + scoreS[1][ct]) + (scoreS[2][ct] + scoreS[3][ct]);
    float mx = s;
    mx = fmaxf(mx, __shfl_xor(mx, 1, 64));
    mx = fmaxf(mx, __shfl_xor(mx, 2, 64));
    mx = fmaxf(mx, __shfl_xor(mx, 4, 64));
    mx = fmaxf(mx, __shfl_xor(mx, 8, 64));
    float e = __expf(s - mx);
    float sum = e;
    sum += __shfl_xor(sum, 1, 64);
    sum += __shfl_xor(sum, 2, 64);
    sum += __shfl_xor(sum, 4, 64);
    sum += __shfl_xor(sum, 8, 64);
    wSm[ct] = e / sum;
  }
  __syncthreads();

  {  // E: xagg[c][k] exact fp32, then bf16-split ONCE (all 256 threads)
    const int c = wv, k = lane;
    float a = 0.f;
#pragma unroll
    for (int t = 0; t < 16; ++t) a = fmaf(wSm[c * 16 + t], xtile[c * 16 + t][k], a);
    __bf16 h = (__bf16)a;
    axH[c * 64 + k] = h;
    axL[c * 64 + k] = (__bf16)(a - (float)h);
  }
  __syncthreads();

  {  // F: params[4][60] = sigmoid(xagg @ P_fused + pb); + CRX trig precompute
    const int jout = wv * 16 + l15;
    f32x4 acc3 = (f32x4){0.f, 0.f, 0.f, 0.f};
#pragma unroll
    for (int ks = 0; ks < 2; ++ks) {
      const size_t row = (size_t)jout * 64 + ks * 32 + 8 * quad;
      bf16x8 bh = *(const bf16x8*)(PfH + row);
      bf16x8 bl = *(const bf16x8*)(PfL + row);
      bf16x8 ax = (bf16x8)(__bf16)0.f, alx = (bf16x8)(__bf16)0.f;
      if (l15 < 4) {
        ax  = *(const bf16x8*)(axH + l15 * 64 + ks * 32 + 8 * quad);
        alx = *(const bf16x8*)(axL + l15 * 64 + ks * 32 + 8 * quad);
      }
      acc3 = __builtin_amdgcn_mfma_f32_16x16x32_bf16(ax, bh, acc3, 0, 0, 0);
      acc3 = __builtin_amdgcn_mfma_f32_16x16x32_bf16(alx, bh, acc3, 0, 0, 0);
      acc3 = __builtin_amdgcn_mfma_f32_16x16x32_bf16(ax, bl, acc3, 0, 0, 0);
    }
    if (jout < 60 && quad == 0) {
      float pbias = pb_fused[jout];
      const int layer = (jout >= 30) ? 1 : 0;
      const int pm = jout - layer * 30;
#pragma unroll
      for (int r = 0; r < 4; ++r) {     // r = chunk (C rows 0..3 = A rows)
        float a = acc3[r] + pbias;
        float p = 1.f / (1.f + __expf(-a));
        paramsS[r * 60 + jout] = p;
        if (pm >= 18) {                 // CRX param: stash (cos,sin) of half
          float sn, cs;
          __sincosf(0.5f * p, &sn, &cs);
          crxS[r * 24 + layer * 12 + (pm - 18)] = make_float2(cs, sn);
        }
      }
    }
  }
  __syncthreads();

  if (tid < 48) {  // G: fused 1q unitary U = Rz*Ry*Rx per (chunk,layer,qubit)
    const int r = tid / 12, g = tid % 12;      // g = layer*6 + q
    const float* pp = paramsS + r * 60 + (g / 6) * 30 + (g % 6) * 3;
    float sa, ca, sb, cb, sg, cg;
    __sincosf(0.5f * pp[0], &sa, &ca);
    __sincosf(0.5f * pp[1], &sb, &cb);
    __sincosf(0.5f * pp[2], &sg, &cg);
    // M = Ry*Rx
    float m00r = cb * ca, m00i = sb * sa;
    float m01r = -sb * ca, m01i = -cb * sa;
    float m10r = sb * ca, m10i = -cb * sa;
    float m11r = cb * ca, m11i = -sb * sa;
    // row0 *= e^{-i g}; row1 *= e^{+i g}; store per-bit {diag, offdiag}
    float4 b0, b1;
    b0.x = cg * m00r + sg * m00i;  b0.y = cg * m00i - sg * m00r;   // U00
    b0.z = cg * m01r + sg * m01i;  b0.w = cg * m01i - sg * m01r;   // U01
    b1.x = cg * m11r - sg * m11i;  b1.y = cg * m11i + sg * m11r;   // U11
    b1.z = cg * m10r - sg * m10i;  b1.w = cg * m10i + sg * m10r;   // U10
    matS[(r * 12 + g) * 2 + 0] = b0;
    matS[(r * 12 + g) * 2 + 1] = b1;
  }
  __syncthreads();

  // ---- H: ALL 4 waves evolve one chunk each (trig-free loop) ----
  {
    float re = (lane == 0) ? 1.f : 0.f, im = 0.f;
    const float4* mats = matS + wv * 24;   // [12][2]
    const float2* crxs = crxS + wv * 24;   // [2][12]
#pragma unroll
    for (int l = 0; l < 2; ++l) {
#pragma unroll
      for (int q = 0; q < 6; ++q) {        // fused RX*RY*RZ
        const int m = 1 << (5 - q);
        float4 M = mats[(l * 6 + q) * 2 + ((lane & m) ? 1 : 0)];
        float pre = __shfl_xor(re, m, 64);
        float pim = __shfl_xor(im, m, 64);
        float nre = M.x * re - M.y * im + M.z * pre - M.w * pim;
        float nim = M.x * im + M.y * re + M.z * pim + M.w * pre;
        re = nre; im = nim;
      }
#pragma unroll
      for (int e = 0; e < 12; ++e) {       // ring CRX fwd then bwd
        const int q = (e < 6) ? e : (11 - e);
        const int mc = 1 << (5 - q);
        const int mt = (e < 6) ? (1 << (5 - ((q + 1) % 6)))
                               : (1 << (5 - ((q + 5) % 6)));
        float2 cs = crxs[l * 12 + e];
        float pre = __shfl_xor(re, mt, 64);
        float pim = __shfl_xor(im, mt, 64);
        float nre = fmaf(cs.y, pim, cs.x * re);
        float nim = fmaf(-cs.y, pre, cs.x * im);
        bool act = (lane & mc) != 0;
        re = act ? nre : re;
        im = act ? nim : im;
      }
    }
    evolved[((size_t)b * NCH + cq * 4 + wv) * QDIM + lane] = make_float2(re, im);
  }
}

// ============ K3: LCU mix + qff ansatz + expvals + head (512 thr) ============
__global__ __launch_bounds__(512) void k3_head(
    const float2* __restrict__ evolved, const float* __restrict__ mix_re,
    const float* __restrict__ mix_im, const float* __restrict__ qff,
    const float* __restrict__ out_w, const float* __restrict__ out_b,
    const float* __restrict__ ln_g, const float* __restrict__ ln_b,
    const float* __restrict__ cls_w1, const float* __restrict__ cls_b1,
    const float* __restrict__ cls_w2, const float* __restrict__ cls_b2,
    float* __restrict__ outp) {
  const int b = blockIdx.x, tid = threadIdx.x, wv = tid >> 6, lane = tid & 63;
  __shared__ float mreS[8][64], mimS[8][64];
  __shared__ float qfeatS[18];
  __shared__ float outS[DD];
  __shared__ float redS[8];
  __shared__ float clsR[2][DD];

  float are = 0.f, aim = 0.f;
#pragma unroll 4
  for (int t = wv * 16; t < wv * 16 + 16; ++t) {
    float2 e = evolved[((size_t)b * NCH + t) * QDIM + lane];
    float cr = mix_re[t], ci = mix_im[t];
    are = fmaf(cr, e.x, are); are = fmaf(-ci, e.y, are);
    aim = fmaf(cr, e.y, aim); aim = fmaf(ci, e.x, aim);
  }
  mreS[wv][lane] = are; mimS[wv][lane] = aim;
  __syncthreads();

  if (wv == 0) {
    float r0 = mix_re[lane], i0 = mix_im[lane];
    float r1 = mix_re[lane + 64], i1 = mix_im[lane + 64];
    float sp = sqrtf(r0 * r0 + i0 * i0) + sqrtf(r1 * r1 + i1 * i1);
    float S = wave_sum(sp) + 1e-8f;
    float re = 0.f, im = 0.f;
#pragma unroll
    for (int w = 0; w < 8; ++w) { re += mreS[w][lane]; im += mimS[w][lane]; }
    float invS = 1.f / S;
    re *= invS; im *= invS;
    float n2 = wave_sum(re * re + im * im);
    float scl = 1.f / (sqrtf(n2) + 1e-9f);
    re *= scl; im *= scl;
    float qp[30];
#pragma unroll
    for (int i = 0; i < 30; ++i) qp[i] = qff[i];
    ansatz_layer(re, im, lane, qp);
#pragma unroll
    for (int q = 0; q < 6; ++q) {
      int m = 1 << (5 - q);
      float pre = __shfl_xor(re, m, 64), pim = __shfl_xor(im, m, 64);
      float vx = re * pre + im * pim;
      float vy = (lane & m) ? (im * pre - re * pim) : (re * pim - im * pre);
      float vz = (lane & m) ? -(re * re + im * im) : (re * re + im * im);
      vx = wave_sum(vx); vy = wave_sum(vy); vz = wave_sum(vz);
      if (lane == 0) { qfeatS[q] = vx; qfeatS[6 + q] = vy; qfeatS[12 + q] = vz; }
    }
  }
  __syncthreads();

  float o = 0.f, dv = 0.f;
  if (tid < 256) {
    o = out_b[tid];
#pragma unroll
    for (int k = 0; k < 18; ++k) o = fmaf(qfeatS[k], out_w[k * DD + tid], o);
    float s1 = wave_sum(o);
    if (lane == 0) redS[wv] = s1;
  }
  __syncthreads();
  float mu = (redS[0] + redS[1] + redS[2] + redS[3]) * (1.f / 256.f);
  if (tid < 256) {
    dv = o - mu;
    float s2 = wave_sum(dv * dv);
    if (lane == 0) redS[wv] = s2;
  }
  __syncthreads();
  float var = (redS[0] + redS[1] + redS[2] + redS[3]) * (1.f / 256.f);
  if (tid < 256) {
    outS[tid] = dv / sqrtf(var + 1e-5f) * ln_g[tid] + ln_b[tid];
  }
  __syncthreads();

  {
    const int dd = tid & 255, hh = tid >> 8;
    float r = (hh == 0) ? cls_b1[dd] : 0.f;
#pragma unroll 8
    for (int d = hh * 128; d < hh * 128 + 128; ++d)
      r = fmaf(outS[d], cls_w1[(size_t)d * DD + dd], r);
    clsR[hh][dd] = r;
  }
  __syncthreads();
  if (tid < 256) {
    float r = fmaxf(clsR[0][tid] + clsR[1][tid], 0.f);
    float p0 = wave_sum(r * cls_w2[tid * 2 + 0]);
    float p1 = wave_sum(r * cls_w2[tid * 2 + 1]);
    if (lane == 0) { mreS[0][wv] = p0; mreS[1][wv] = p1; }
  }
  __syncthreads();
  if (tid == 0) {
    outp[b * 2 + 0] = (mreS[0][0] + mreS[0][1]) + (mreS[0][2] + mreS[0][3]) + cls_b2[0];
    outp[b * 2 + 1] = (mreS[1][0] + mreS[1][1]) + (mreS[1][2] + mreS[1][3]) + cls_b2[1];
  }
}

extern "C" void kernel_launch(void* const* d_in, const int* in_sizes, int n_in,
                              void* d_out, int out_size, void* d_ws, size_t ws_size,
                              hipStream_t stream) {
  const float* x      = (const float*)d_in[0];
  const float* emb_w  = (const float*)d_in[1];
  const float* emb_b  = (const float*)d_in[2];
  const float* att_w1 = (const float*)d_in[3];
  const float* att_b1 = (const float*)d_in[4];
  const float* att_w2 = (const float*)d_in[5];
  // d_in[6] att_b2: unused (softmax shift-invariant)
  const float* proj_w = (const float*)d_in[7];
  const float* proj_b = (const float*)d_in[8];
  const float* mix_re = (const float*)d_in[9];
  const float* mix_im = (const float*)d_in[10];
  const float* qff    = (const float*)d_in[11];
  const float* out_w  = (const float*)d_in[12];
  const float* out_b  = (const float*)d_in[13];
  const float* ln_g   = (const float*)d_in[14];
  const float* ln_b   = (const float*)d_in[15];
  const float* cls_w1 = (const float*)d_in[16];
  const float* cls_b1 = (const float*)d_in[17];
  const float* cls_w2 = (const float*)d_in[18];
  const float* cls_b2 = (const float*)d_in[19];

  char* ws = (char*)d_ws;
  float2* evolved = (float2*)ws;                     // 16384*64*8 = 8,388,608
  size_t off = 8388608;
  __bf16* WfH = (__bf16*)(ws + off); off += 16384;   // 128x64 bf16
  __bf16* WfL = (__bf16*)(ws + off); off += 16384;
  __bf16* PfH = (__bf16*)(ws + off); off += 8192;    // 64x64 bf16
  __bf16* PfL = (__bf16*)(ws + off); off += 8192;
  float* b_fused  = (float*)(ws + off); off += 512;
  float* pb_fused = (float*)(ws + off); off += 256;

  k0_prep<<<390, 256, 0, stream>>>(emb_w, emb_b, att_w1, att_b1, proj_w, proj_b,
                                   WfH, WfL, PfH, PfL, b_fused, pb_fused);
  k1_fused<<<BB * 32, 256, 0, stream>>>(
      x, att_w2, WfH, WfL, PfH, PfL, b_fused, pb_fused, evolved);
  k3_head<<<BB, 512, 0, stream>>>(evolved, mix_re, mix_im, qff, out_w, out_b,
                                  ln_g, ln_b, cls_w1, cls_b1, cls_w2, cls_b2,
                                  (float*)d_out);
}